// Round 8
// baseline (214.396 us; speedup 1.0000x reference)
//
#include <hip/hip_runtime.h>
#include <hip/hip_bf16.h>

#define DDIM 256
#define NROWS 8192

typedef __attribute__((ext_vector_type(8))) __bf16 bf16x8;
typedef __attribute__((ext_vector_type(4))) float floatx4;

// raw v_exp_f32: returns 2^x (one transcendental)
__device__ __forceinline__ float fexp2(float x) {
    float r; asm("v_exp_f32 %0, %1" : "=v"(r) : "v"(x)); return r;
}

// Kernel 1: L2-normalize rows of U and P to bf16, compute pos_sim, zero
// rowsum / out / ticket counter. One wave per row. (Un/Pn are plain
// row-major -- no swizzle anywhere in this version.)
__global__ __launch_bounds__(256) void normalize_kernel(
    const float* __restrict__ U, const float* __restrict__ P,
    unsigned short* __restrict__ Un, unsigned short* __restrict__ Pn,
    float* __restrict__ possim, float* __restrict__ rowsum,
    float* __restrict__ out, int* __restrict__ counter)
{
    if (blockIdx.x == 0 && threadIdx.x == 0) { out[0] = 0.0f; counter[0] = 0; }
    const int lane = threadIdx.x & 63;
    const int row  = blockIdx.x * 4 + (threadIdx.x >> 6);
    const size_t base = (size_t)row * DDIM + lane * 4;
    const float4 u4 = *(const float4*)(U + base);
    const float4 p4 = *(const float4*)(P + base);
    float su = u4.x*u4.x + u4.y*u4.y + u4.z*u4.z + u4.w*u4.w;
    float sp = p4.x*p4.x + p4.y*p4.y + p4.z*p4.z + p4.w*p4.w;
    float up = u4.x*p4.x + u4.y*p4.y + u4.z*p4.z + u4.w*p4.w;
    #pragma unroll
    for (int d = 1; d < 64; d <<= 1) {
        su += __shfl_xor(su, d);
        sp += __shfl_xor(sp, d);
        up += __shfl_xor(up, d);
    }
    const float iu = rsqrtf(fmaxf(su, 1e-24f));
    const float ip = rsqrtf(fmaxf(sp, 1e-24f));
    if (lane == 0) {
        possim[row] = up * iu * ip;
        rowsum[row] = 0.0f;
    }
    union { ushort4 s4; __hip_bfloat16 h[4]; } cu, cp;
    cu.h[0] = __float2bfloat16(u4.x * iu); cu.h[1] = __float2bfloat16(u4.y * iu);
    cu.h[2] = __float2bfloat16(u4.z * iu); cu.h[3] = __float2bfloat16(u4.w * iu);
    cp.h[0] = __float2bfloat16(p4.x * ip); cp.h[1] = __float2bfloat16(p4.y * ip);
    cp.h[2] = __float2bfloat16(p4.z * ip); cp.h[3] = __float2bfloat16(p4.w * ip);
    *(ushort4*)(Un + base) = cu.s4;
    *(ushort4*)(Pn + base) = cp.s4;
}

// Kernel 2: BARRIER-FREE, LDS-FREE persistent-A GEMM + exp-rowsum.
// Discriminating experiment after 7 schedule variants all hit 84-122 us
// with every pipe <35%: the shared invariant was the barrier-coupled LDS
// staging pipeline. Here B fragments are read DIRECTLY from L2:
//   256 blocks x 512 thr (8 waves, 1/CU). Block = 256 rows x 1024 cols;
//   wave = 32 rows, self-paced, ZERO barriers and ZERO LDS in the loop.
//   B panel per XCD = 512 KB (L2-resident, read ~8x per CU, ~1 GB total
//   L2 traffic ~= 20 TB/s aggregate < 34.5 ceiling). Latency hidden by a
//   16-load in-flight window (fA/fB ping-pong, next-slot loads issued
//   under the current slot's MFMA + exp block) and 2 waves/SIMD.
// Frag math identical to R6 minus the (LDS-only) granule swizzle:
//   A frag: Arow + t*16*DDIM + (ks*4+q)*8        (verified R2/R6)
//   B frag: Bs + (n*16+m)*512 + q*16 + par*64 + P*128   (ks = 2P+par)
__global__ __launch_bounds__(512, 2) void sim_exp_rowsum(
    const unsigned short* __restrict__ Un,
    const unsigned short* __restrict__ Pn,
    float* __restrict__ rowsum,
    const float* __restrict__ possim,
    int* __restrict__ counter,
    float* __restrict__ out)
{
    __shared__ float ws8[8];
    __shared__ int ticket_s;

    const int tid  = threadIdx.x;
    const int lane = tid & 63;
    const int wv   = tid >> 6;          // 0..7, each wave owns 32 A-rows
    const int m = lane & 15;
    const int q = lane >> 4;

    const int stripe = blockIdx.x >> 3;   // 0..31  (256-row stripes)
    const int oct    = blockIdx.x & 7;    // 0..7   (1024-col groups == XCD)

    // ---- A-frags straight from global (one-time, L2/L3-hot) ----
    const unsigned short* Arow = Un + (size_t)(stripe * 256 + wv * 32 + m) * DDIM;
    bf16x8 afr[2][8];
    #pragma unroll
    for (int t = 0; t < 2; ++t)
        #pragma unroll
        for (int ks = 0; ks < 8; ++ks)
            afr[t][ks] = *(const bf16x8*)(Arow + t * 16 * DDIM + (ks * 4 + q) * 8);

    // ---- B per-lane byte offsets (loop-invariant): voff[par][n] ----
    unsigned voff[2][4];
    #pragma unroll
    for (int par = 0; par < 2; ++par)
        #pragma unroll
        for (int n = 0; n < 4; ++n)
            voff[par][n] = (unsigned)((n * 16 + m) * 512 + q * 16 + par * 64);

    const char* Bbase = (const char*)(Pn + (size_t)(oct * 1024) * DDIM);
    float rowpart[2][4] = {{0.f, 0.f, 0.f, 0.f}, {0.f, 0.f, 0.f, 0.f}};

// load the 8 B-frags of phase P of the slot whose col-base byte ptr is BS
#define LOADG(BS, P, F)                                                      \
    do {                                                                     \
        _Pragma("unroll")                                                    \
        for (int par = 0; par < 2; ++par)                                    \
            _Pragma("unroll")                                                \
            for (int n = 0; n < 4; ++n)                                      \
                F[par * 4 + n] = *(const bf16x8*)((BS) + voff[par][n]        \
                                                  + (P) * 128);              \
    } while (0)

#define MMAPH(P, F)                                                          \
    do {                                                                     \
        __builtin_amdgcn_s_setprio(1);                                       \
        _Pragma("unroll")                                                    \
        for (int n = 0; n < 4; ++n) {                                        \
            acc[0][n] = __builtin_amdgcn_mfma_f32_16x16x32_bf16(             \
                afr[0][2 * (P)], F[n], acc[0][n], 0, 0, 0);                  \
            acc[1][n] = __builtin_amdgcn_mfma_f32_16x16x32_bf16(             \
                afr[1][2 * (P)], F[n], acc[1][n], 0, 0, 0);                  \
            acc[0][n] = __builtin_amdgcn_mfma_f32_16x16x32_bf16(             \
                afr[0][2 * (P) + 1], F[n + 4], acc[0][n], 0, 0, 0);          \
            acc[1][n] = __builtin_amdgcn_mfma_f32_16x16x32_bf16(             \
                afr[1][2 * (P) + 1], F[n + 4], acc[1][n], 0, 0, 0);          \
        }                                                                    \
        __builtin_amdgcn_s_setprio(0);                                       \
    } while (0)

    // ---- Main loop: 16 col-slots of 64, software-pipelined, no sync ----
    bf16x8 fA[8], fB[8];
    LOADG(Bbase, 0, fA);            // slot 0 phase 0
    LOADG(Bbase, 1, fB);            // slot 0 phase 1

    for (int i = 0; i < 16; ++i) {
        const char* Bs  = Bbase + (unsigned)i * 32768u;
        const char* Bsn = Bs + 32768u;          // next slot
        floatx4 acc[2][4];
        #pragma unroll
        for (int t = 0; t < 2; ++t)
            #pragma unroll
            for (int n = 0; n < 4; ++n)
                acc[t][n] = {0.0f, 0.0f, 0.0f, 0.0f};

        MMAPH(0, fA);  LOADG(Bs, 2, fA);
        MMAPH(1, fB);  LOADG(Bs, 3, fB);
        MMAPH(2, fA);  if (i < 15) LOADG(Bsn, 0, fA);
        MMAPH(3, fB);  if (i < 15) LOADG(Bsn, 1, fB);

        // exp(5*sim) = 2^(sim*5*log2 e) -- also covers next-slot load latency
        #pragma unroll
        for (int t = 0; t < 2; ++t)
            #pragma unroll
            for (int n = 0; n < 4; ++n)
                #pragma unroll
                for (int r = 0; r < 4; ++r)
                    rowpart[t][r] += fexp2(acc[t][n][r] * 7.2134752044448169f);
    }
#undef LOADG
#undef MMAPH

    // ---- Epilogue: reduce 16 column-lanes, one atomic per row per wave ----
    #pragma unroll
    for (int t = 0; t < 2; ++t) {
        #pragma unroll
        for (int r = 0; r < 4; ++r) {
            float s = rowpart[t][r];
            s += __shfl_xor(s, 1);
            s += __shfl_xor(s, 2);
            s += __shfl_xor(s, 4);
            s += __shfl_xor(s, 8);
            if (m == 0) {
                const int grow = stripe * 256 + wv * 32 + t * 16 + q * 4 + r;
                atomicAdd(&rowsum[grow], s);
            }
        }
    }

    // ---- Fused finalize: last block computes the loss ----
    __threadfence();
    __syncthreads();   // this block's atomics are visible
    if (tid == 0)
        ticket_s = __hip_atomic_fetch_add(counter, 1, __ATOMIC_ACQ_REL,
                                          __HIP_MEMORY_SCOPE_AGENT);
    __syncthreads();
    if (ticket_s == 255) {
        float part = 0.0f;
        for (int i = tid; i < NROWS; i += 512) {
            const float rs = __hip_atomic_load(&rowsum[i], __ATOMIC_RELAXED,
                                               __HIP_MEMORY_SCOPE_AGENT);
            part += __logf(rs) - 5.0f * possim[i];
        }
        #pragma unroll
        for (int d = 1; d < 64; d <<= 1) part += __shfl_xor(part, d);
        if (lane == 0) ws8[wv] = part;
        __syncthreads();
        if (tid == 0) {
            float tot = 0.0f;
            #pragma unroll
            for (int w = 0; w < 8; ++w) tot += ws8[w];
            out[0] = tot * (1.0f / (float)NROWS);
        }
    }
}

extern "C" void kernel_launch(void* const* d_in, const int* in_sizes, int n_in,
                              void* d_out, int out_size, void* d_ws, size_t ws_size,
                              hipStream_t stream) {
    const float* U = (const float*)d_in[0];
    const float* P = (const float*)d_in[1];
    float* out = (float*)d_out;
    char* ws = (char*)d_ws;
    // ws: Un bf16 (4 MB) | Pn bf16 (4 MB) | rowsum f32 (32 KB) | possim f32 (32 KB) | counter
    unsigned short* Un = (unsigned short*)ws;
    unsigned short* Pn = (unsigned short*)(ws + 4194304);
    float* rowsum = (float*)(ws + 8388608);
    float* possim = (float*)(ws + 8388608 + 32768);
    int* counter  = (int*)(ws + 8388608 + 65536);

    normalize_kernel<<<NROWS / 4, 256, 0, stream>>>(U, P, Un, Pn, possim, rowsum,
                                                    out, counter);
    sim_exp_rowsum<<<256, 512, 0, stream>>>(Un, Pn, rowsum, possim, counter, out);
}

// Round 10
// 146.813 us; speedup vs baseline: 1.4603x; 1.4603x over previous
//
#include <hip/hip_runtime.h>
#include <hip/hip_bf16.h>

#define DDIM 256
#define NROWS 8192

typedef __attribute__((ext_vector_type(8))) __bf16 bf16x8;
typedef __attribute__((ext_vector_type(4))) float floatx4;

// async global->LDS, 16B per lane. LDS dest is wave-uniform base + lane*16.
__device__ __forceinline__ void async16(const void* g, void* l) {
    __builtin_amdgcn_global_load_lds(
        (const __attribute__((address_space(1))) unsigned int*)g,
        (__attribute__((address_space(3))) unsigned int*)l,
        16, 0, 0);
}

// raw v_exp_f32: returns 2^x (one transcendental)
__device__ __forceinline__ float fexp2(float x) {
    float r; asm("v_exp_f32 %0, %1" : "=v"(r) : "v"(x)); return r;
}

// Kernel 1: L2-normalize rows of U and P to bf16, compute pos_sim, zero
// rowsum / out / ticket counter. One wave per row.
__global__ __launch_bounds__(256) void normalize_kernel(
    const float* __restrict__ U, const float* __restrict__ P,
    unsigned short* __restrict__ Un, unsigned short* __restrict__ Pn,
    float* __restrict__ possim, float* __restrict__ rowsum,
    float* __restrict__ out, int* __restrict__ counter)
{
    if (blockIdx.x == 0 && threadIdx.x == 0) { out[0] = 0.0f; counter[0] = 0; }
    const int lane = threadIdx.x & 63;
    const int row  = blockIdx.x * 4 + (threadIdx.x >> 6);
    const size_t base = (size_t)row * DDIM + lane * 4;
    const float4 u4 = *(const float4*)(U + base);
    const float4 p4 = *(const float4*)(P + base);
    float su = u4.x*u4.x + u4.y*u4.y + u4.z*u4.z + u4.w*u4.w;
    float sp = p4.x*p4.x + p4.y*p4.y + p4.z*p4.z + p4.w*p4.w;
    float up = u4.x*p4.x + u4.y*p4.y + u4.z*p4.z + u4.w*p4.w;
    #pragma unroll
    for (int d = 1; d < 64; d <<= 1) {
        su += __shfl_xor(su, d);
        sp += __shfl_xor(sp, d);
        up += __shfl_xor(up, d);
    }
    const float iu = rsqrtf(fmaxf(su, 1e-24f));
    const float ip = rsqrtf(fmaxf(sp, 1e-24f));
    if (lane == 0) {
        possim[row] = up * iu * ip;
        rowsum[row] = 0.0f;
    }
    union { ushort4 s4; __hip_bfloat16 h[4]; } cu, cp;
    cu.h[0] = __float2bfloat16(u4.x * iu); cu.h[1] = __float2bfloat16(u4.y * iu);
    cu.h[2] = __float2bfloat16(u4.z * iu); cu.h[3] = __float2bfloat16(u4.w * iu);
    cp.h[0] = __float2bfloat16(p4.x * ip); cp.h[1] = __float2bfloat16(p4.y * ip);
    cp.h[2] = __float2bfloat16(p4.z * ip); cp.h[3] = __float2bfloat16(p4.w * ip);
    *(ushort4*)(Un + base) = cu.s4;
    *(ushort4*)(Pn + base) = cp.s4;
}

// Stage 8 rows (4 KB) of a 64-row B tile per wave into LDS at l (4 async16).
// Linear layout with granule swizzle: stored granule g holds logical g^(r&7).
// NOTE: each async16 writes 1024 B (64 lanes x 16 B = 2 rows); chunk j's
// dest byte offset within the wave's 4 KB region is j*1024.
__device__ __forceinline__ void stage8(const unsigned short* __restrict__ g,
                                       unsigned short* l, int wv, int lane)
{
    const int lrow = lane >> 5;       // 0..1
    const int gcol = lane & 31;       // granule 0..31
    const int r0 = wv * 8;
    #pragma unroll
    for (int j = 0; j < 4; ++j) {
        const int rb = r0 + j * 2;
        const int r  = rb + lrow;
        const int gg = gcol ^ (r & 7);
        async16(g + (size_t)r * DDIM + gg * 8, l + (size_t)rb * DDIM);
    }
}

// Kernel 2: persistent-A GEMM + exp-rowsum, m201-faithful phase discipline.
// Geometry = R6 (best measured, 83.7 us): 256 blocks x 512 thr (8 waves,
// 1 block/CU), block = 256 rows x 1024 cols, wave = 32 rows, afr[2][8]
// direct from global, B quad-buffered 4 x 32 KB (128 KB LDS), 16 slots of
// 64 cols, vmcnt(8/4/0) ladder once per slot (counted, never drains
// mid-loop). Slot interior = 4 paired-barrier phases
//   {8 ds_read (this phase) + 1 stage-chunk of tile i+3} -> sched_barrier
//   -> s_barrier -> lgkmcnt(0) -> sched_barrier -> setprio(1) -> 16 MFMA
//   -> setprio(0) -> s_barrier
// ds_read latency hides under the barrier rendezvous (not a serial wait as
// in R5); stage loads spread 1-per-phase span phases via counted vmcnt
// (T3+T4); phase structure gives setprio (T5) its role-split.
// R9 BUGFIX: stage-chunk dest stride is 1024 B per chunk (each async16
// covers 2 rows), was 512 -> overlapping writes left half of each tile
// uninitialized -> NaN. Source offsets were correct.
__global__ __launch_bounds__(512, 2) void sim_exp_rowsum(
    const unsigned short* __restrict__ Un,
    const unsigned short* __restrict__ Pn,
    float* __restrict__ rowsum,
    const float* __restrict__ possim,
    int* __restrict__ counter,
    float* __restrict__ out)
{
    __shared__ __align__(16) unsigned short lds[65536];   // 128 KB: 4 x 32 KB B bufs
    __shared__ float ws8[8];
    __shared__ int ticket_s;

    const int tid  = threadIdx.x;
    const int lane = tid & 63;
    const int wv   = tid >> 6;          // 0..7, each wave owns 32 A-rows
    const int m = lane & 15;
    const int q = lane >> 4;

    const int stripe = blockIdx.x >> 3;   // 0..31  (256-row stripes)
    const int oct    = blockIdx.x & 7;    // 0..7   (1024-col groups == XCD)

    // ---- A-frags straight from global (one-time, L2/L3-hot) ----
    const unsigned short* Arow = Un + (size_t)(stripe * 256 + wv * 32 + m) * DDIM;
    bf16x8 afr[2][8];
    #pragma unroll
    for (int t = 0; t < 2; ++t)
        #pragma unroll
        for (int ks = 0; ks < 8; ++ks)
            afr[t][ks] = *(const bf16x8*)(Arow + t * 16 * DDIM + (ks * 4 + q) * 8);

    // ---- B-frag addressing: addr = Bp + bb[par] + n*8192 + P*128 ----
    // reproduces row*512 + ((ks*4+q)^(m&7))*16 for row = n*16+m, ks = 2P+par.
    const int c10 = m & 3, c2 = (m >> 2) & 1;
    const unsigned bb0 = (unsigned)(m * 512 + ((q ^ c10) << 4) + ((0 ^ c2) << 6));
    const unsigned bb1 = (unsigned)(m * 512 + ((q ^ c10) << 4) + ((1 ^ c2) << 6));

    // ---- stage-chunk offsets (1 async16 per phase; same math as stage8) ----
    const int lrow = lane >> 5, gcol = lane & 31;
    unsigned soff[4];
    #pragma unroll
    for (int j = 0; j < 4; ++j) {
        const int r = wv * 8 + j * 2 + lrow;
        const int gg = gcol ^ (r & 7);
        soff[j] = (unsigned)(r * 512 + gg * 16);
    }

    const unsigned short* Bglob = Pn + (size_t)(oct * 1024) * DDIM;
    float rowpart[2][4] = {{0.f, 0.f, 0.f, 0.f}, {0.f, 0.f, 0.f, 0.f}};

    // ---- Prologue: stage tiles 0..2, full drain (also covers A-loads) ----
    stage8(Bglob,              lds,         wv, lane);
    stage8(Bglob + 64 * DDIM,  lds + 16384, wv, lane);
    stage8(Bglob + 128 * DDIM, lds + 32768, wv, lane);
    asm volatile("s_waitcnt vmcnt(0)" ::: "memory");
    __builtin_amdgcn_s_barrier();

#define LOADPH(BP, P, F)                                                     \
    do {                                                                     \
        F[0] = *(const bf16x8*)((BP) + bb0 + 0 * 8192 + (P) * 128);          \
        F[1] = *(const bf16x8*)((BP) + bb0 + 1 * 8192 + (P) * 128);          \
        F[2] = *(const bf16x8*)((BP) + bb0 + 2 * 8192 + (P) * 128);          \
        F[3] = *(const bf16x8*)((BP) + bb0 + 3 * 8192 + (P) * 128);          \
        F[4] = *(const bf16x8*)((BP) + bb1 + 0 * 8192 + (P) * 128);          \
        F[5] = *(const bf16x8*)((BP) + bb1 + 1 * 8192 + (P) * 128);          \
        F[6] = *(const bf16x8*)((BP) + bb1 + 2 * 8192 + (P) * 128);          \
        F[7] = *(const bf16x8*)((BP) + bb1 + 3 * 8192 + (P) * 128);          \
    } while (0)

#define MMAPH(P, F)                                                          \
    do {                                                                     \
        _Pragma("unroll")                                                    \
        for (int n = 0; n < 4; ++n) {                                        \
            acc[0][n] = __builtin_amdgcn_mfma_f32_16x16x32_bf16(             \
                afr[0][2 * (P)], F[n], acc[0][n], 0, 0, 0);                  \
            acc[1][n] = __builtin_amdgcn_mfma_f32_16x16x32_bf16(             \
                afr[1][2 * (P)], F[n], acc[1][n], 0, 0, 0);                  \
            acc[0][n] = __builtin_amdgcn_mfma_f32_16x16x32_bf16(             \
                afr[0][2 * (P) + 1], F[n + 4], acc[0][n], 0, 0, 0);          \
            acc[1][n] = __builtin_amdgcn_mfma_f32_16x16x32_bf16(             \
                afr[1][2 * (P) + 1], F[n + 4], acc[1][n], 0, 0, 0);          \
        }                                                                    \
    } while (0)

    // ---- Main loop: 16 col-slots of 64, 4 paired-barrier phases each ----
    for (int i = 0; i < 16; ++i) {
        // slot top: tile i landed (counted -- tiles i+1, i+2 stay in flight)
        if (i > 0) {
            if (i <= 13)      asm volatile("s_waitcnt vmcnt(8)" ::: "memory");
            else if (i == 14) asm volatile("s_waitcnt vmcnt(4)" ::: "memory");
            else              asm volatile("s_waitcnt vmcnt(0)" ::: "memory");
            __builtin_amdgcn_s_barrier();
        }

        const char* Bp = (const char*)lds + (i & 3) * 32768;
        const bool do_stage = (i + 3 < 16);
        const unsigned short* sg = Bglob + (size_t)(i + 3) * 64 * DDIM;
        unsigned short* sl = lds + ((i + 3) & 3) * 16384 + wv * 2048;

        floatx4 acc[2][4];
        #pragma unroll
        for (int t = 0; t < 2; ++t)
            #pragma unroll
            for (int n = 0; n < 4; ++n)
                acc[t][n] = {0.0f, 0.0f, 0.0f, 0.0f};

        bf16x8 F[8];
        #pragma unroll
        for (int p = 0; p < 4; ++p) {
            LOADPH(Bp, p, F);                       // 8 ds_read_b128, this phase
            if (do_stage)                           // 1 G-load chunk of tile i+3
                async16((const char*)sg + soff[p],
                        (char*)sl + p * 1024);      // FIX: 1024 B per chunk
            __builtin_amdgcn_sched_barrier(0);      // pin reads above barrier
            __builtin_amdgcn_s_barrier();           // latency hides in rendezvous
            asm volatile("s_waitcnt lgkmcnt(0)" ::: "memory");
            __builtin_amdgcn_sched_barrier(0);      // rule #18: no MFMA hoist
            __builtin_amdgcn_s_setprio(1);
            MMAPH(p, F);                            // 16 MFMA
            __builtin_amdgcn_s_setprio(0);
            __builtin_amdgcn_sched_barrier(0);
            __builtin_amdgcn_s_barrier();           // phase end
        }

        // exp(5*sim) = 2^(sim*5*log2 e); C/D: col = m, row = q*4+r (+t*16)
        #pragma unroll
        for (int t = 0; t < 2; ++t)
            #pragma unroll
            for (int n = 0; n < 4; ++n)
                #pragma unroll
                for (int r = 0; r < 4; ++r)
                    rowpart[t][r] += fexp2(acc[t][n][r] * 7.2134752044448169f);
    }
#undef LOADPH
#undef MMAPH

    // ---- Epilogue: reduce 16 column-lanes, one atomic per row per wave ----
    #pragma unroll
    for (int t = 0; t < 2; ++t) {
        #pragma unroll
        for (int r = 0; r < 4; ++r) {
            float s = rowpart[t][r];
            s += __shfl_xor(s, 1);
            s += __shfl_xor(s, 2);
            s += __shfl_xor(s, 4);
            s += __shfl_xor(s, 8);
            if (m == 0) {
                const int grow = stripe * 256 + wv * 32 + t * 16 + q * 4 + r;
                atomicAdd(&rowsum[grow], s);
            }
        }
    }

    // ---- Fused finalize: last block computes the loss ----
    __threadfence();
    __syncthreads();   // this block's atomics are visible
    if (tid == 0)
        ticket_s = __hip_atomic_fetch_add(counter, 1, __ATOMIC_ACQ_REL,
                                          __HIP_MEMORY_SCOPE_AGENT);
    __syncthreads();
    if (ticket_s == 255) {
        float part = 0.0f;
        for (int i = tid; i < NROWS; i += 512) {
            const float rs = __hip_atomic_load(&rowsum[i], __ATOMIC_RELAXED,
                                               __HIP_MEMORY_SCOPE_AGENT);
            part += __logf(rs) - 5.0f * possim[i];
        }
        #pragma unroll
        for (int d = 1; d < 64; d <<= 1) part += __shfl_xor(part, d);
        if (lane == 0) ws8[wv] = part;
        __syncthreads();
        if (tid == 0) {
            float tot = 0.0f;
            #pragma unroll
            for (int w = 0; w < 8; ++w) tot += ws8[w];
            out[0] = tot * (1.0f / (float)NROWS);
        }
    }
}

extern "C" void kernel_launch(void* const* d_in, const int* in_sizes, int n_in,
                              void* d_out, int out_size, void* d_ws, size_t ws_size,
                              hipStream_t stream) {
    const float* U = (const float*)d_in[0];
    const float* P = (const float*)d_in[1];
    float* out = (float*)d_out;
    char* ws = (char*)d_ws;
    // ws: Un bf16 (4 MB) | Pn bf16 (4 MB) | rowsum f32 (32 KB) | possim f32 (32 KB) | counter
    unsigned short* Un = (unsigned short*)ws;
    unsigned short* Pn = (unsigned short*)(ws + 4194304);
    float* rowsum = (float*)(ws + 8388608);
    float* possim = (float*)(ws + 8388608 + 32768);
    int* counter  = (int*)(ws + 8388608 + 65536);

    normalize_kernel<<<NROWS / 4, 256, 0, stream>>>(U, P, Un, Pn, possim, rowsum,
                                                    out, counter);
    sim_exp_rowsum<<<256, 512, 0, stream>>>(Un, Pn, rowsum, possim, counter, out);
}

// Round 11
// 129.331 us; speedup vs baseline: 1.6577x; 1.1352x over previous
//
#include <hip/hip_runtime.h>
#include <hip/hip_bf16.h>

#define DDIM 256
#define NROWS 8192

typedef __attribute__((ext_vector_type(4))) int int4v;
typedef __attribute__((ext_vector_type(8))) int int8v;
typedef __attribute__((ext_vector_type(16))) float f32x16;

// async global->LDS, 16B per lane. LDS dest is wave-uniform base + lane*16.
__device__ __forceinline__ void async16(const void* g, void* l) {
    __builtin_amdgcn_global_load_lds(
        (const __attribute__((address_space(1))) unsigned int*)g,
        (__attribute__((address_space(3))) unsigned int*)l,
        16, 0, 0);
}

// raw v_exp_f32: returns 2^x (one transcendental)
__device__ __forceinline__ float fexp2(float x) {
    float r; asm("v_exp_f32 %0, %1" : "=v"(r) : "v"(x)); return r;
}

// Kernel 1: L2-normalize rows of U and P to FP8 e4m3 (OCP), compute pos_sim
// in fp32 (exact), zero rowsum / out / ticket counter. One wave per row.
// fp8 conversion via v_cvt_pk_fp8_f32 (2 f32 -> 2 e4m3 packed).
__global__ __launch_bounds__(256) void normalize_kernel(
    const float* __restrict__ U, const float* __restrict__ P,
    unsigned char* __restrict__ Un, unsigned char* __restrict__ Pn,
    float* __restrict__ possim, float* __restrict__ rowsum,
    float* __restrict__ out, int* __restrict__ counter)
{
    if (blockIdx.x == 0 && threadIdx.x == 0) { out[0] = 0.0f; counter[0] = 0; }
    const int lane = threadIdx.x & 63;
    const int row  = blockIdx.x * 4 + (threadIdx.x >> 6);
    const size_t fbase = (size_t)row * DDIM + lane * 4;
    const float4 u4 = *(const float4*)(U + fbase);
    const float4 p4 = *(const float4*)(P + fbase);
    float su = u4.x*u4.x + u4.y*u4.y + u4.z*u4.z + u4.w*u4.w;
    float sp = p4.x*p4.x + p4.y*p4.y + p4.z*p4.z + p4.w*p4.w;
    float up = u4.x*p4.x + u4.y*p4.y + u4.z*p4.z + u4.w*p4.w;
    #pragma unroll
    for (int d = 1; d < 64; d <<= 1) {
        su += __shfl_xor(su, d);
        sp += __shfl_xor(sp, d);
        up += __shfl_xor(up, d);
    }
    const float iu = rsqrtf(fmaxf(su, 1e-24f));
    const float ip = rsqrtf(fmaxf(sp, 1e-24f));
    if (lane == 0) {
        possim[row] = up * iu * ip;
        rowsum[row] = 0.0f;
    }
    unsigned pu = (unsigned)__builtin_amdgcn_cvt_pk_fp8_f32(u4.x*iu, u4.y*iu, 0, false);
    pu = (unsigned)__builtin_amdgcn_cvt_pk_fp8_f32(u4.z*iu, u4.w*iu, (int)pu, true);
    unsigned pp = (unsigned)__builtin_amdgcn_cvt_pk_fp8_f32(p4.x*ip, p4.y*ip, 0, false);
    pp = (unsigned)__builtin_amdgcn_cvt_pk_fp8_f32(p4.z*ip, p4.w*ip, (int)pp, true);
    *(unsigned*)(Un + (size_t)row * DDIM + lane * 4) = pu;
    *(unsigned*)(Pn + (size_t)row * DDIM + lane * 4) = pp;
}

// Kernel 2: persistent-A FP8 GEMM (mfma_scale_f32_32x32x64_f8f6f4, unit
// E8M0 scales = plain fp8 at 2x bf16 rate) + exp-rowsum + fused finalize.
// Geometry: R6's proven shell -- 256 blocks x 512 thr (8 waves, 1/CU),
// block = 256 rows x 1024 cols, wave = 32 rows, 16 col-slots of 64,
// quad-buffered B (4 x 16 KB fp8 = 64 KB LDS), slot top = counted
// vmcnt(4/2/0) + one barrier, stage-after-barrier, plain interior.
// fp8 halves LDS traffic per wave (256 B/lane/slot) and halves MFMA
// issue cycles per FLOP -- attacks the two largest per-slot components.
// Fragment layouts (32x32x64 f8f6f4):
//   A: row = lane&31, k = (lane>>5)*32 + i (32 consecutive bytes, 8 VGPR)
//   B: col = lane&31, k = (lane>>5)*32 + i (symmetric)
//   C/D: col = lane&31, row = (reg&3) + 8*(reg>>2) + 4*(lane>>5)  [HW-verified]
// LDS tile 64 rows x 256 B; granule-16 XOR swizzle g^(row&15) (involution,
// pre-swizzled async16 source per rule #21) kills the row-stride-256 conflict.
__global__ __launch_bounds__(512, 2) void sim_exp_rowsum(
    const unsigned char* __restrict__ Un,
    const unsigned char* __restrict__ Pn,
    float* __restrict__ rowsum,
    const float* __restrict__ possim,
    int* __restrict__ counter,
    float* __restrict__ out)
{
    __shared__ __align__(16) unsigned char lds[65536];   // 4 x 16 KB fp8 B bufs
    __shared__ float ws8[8];
    __shared__ int ticket_s;

    const int tid  = threadIdx.x;
    const int lane = tid & 63;
    const int wv   = tid >> 6;          // 0..7, each wave owns 32 A-rows
    const int m32  = lane & 31;
    const int hi   = lane >> 5;

    const int stripe = blockIdx.x >> 3;   // 0..31  (256-row stripes)
    const int oct    = blockIdx.x & 7;    // 0..7   (1024-col groups == XCD)

    // ---- A-frags straight from global fp8 (one-time, L2/L3-hot) ----
    // afr[kc]: k = kc*64 + hi*32 + 0..31 (two dwordx4), row = wv*32 + m32.
    const unsigned char* Arow = Un
        + (size_t)(stripe * 256 + wv * 32 + m32) * DDIM + hi * 32;
    union A8 { int8v v; int4v h[2]; };
    A8 afr[4];
    #pragma unroll
    for (int kc = 0; kc < 4; ++kc) {
        afr[kc].h[0] = *(const int4v*)(Arow + kc * 64);
        afr[kc].h[1] = *(const int4v*)(Arow + kc * 64 + 16);
    }

    // ---- B LDS addressing (swizzle pre-folded) ----
    // logical: row = n*32+m32 (256 B rows), bytes k = kc*64 + hi*32 + h*16
    // phys granule = logical granule ^ (row&15); row&15 == m32&15.
    // addr = m32*256 + ((hi*2+h)^xlo)*16 + (kc*64 ^ xh16) + n*8192
    const int x = m32 & 15, xlo = x & 3;
    const unsigned xh16 = (unsigned)((x & 12) * 16);
    const unsigned bA = (unsigned)(m32 * 256 + (((hi * 2 + 0) ^ xlo) * 16));
    const unsigned bB = (unsigned)(m32 * 256 + (((hi * 2 + 1) ^ xlo) * 16));
    unsigned kterm[4];
    #pragma unroll
    for (int kc = 0; kc < 4; ++kc)
        kterm[kc] = (unsigned)(kc * 64) ^ xh16;

    // ---- staging offsets: wave stages 8 rows (2 KB) per tile, 2 async16 ----
    // chunk j covers rows wv*8 + j*4 + (lane>>4); dest granule = lane&15;
    // source supplies logical granule (lane&15) ^ (row&15).
    unsigned soff0, soff1;
    {
        const int r0 = wv * 8 + 0 * 4 + (lane >> 4);
        const int r1 = wv * 8 + 1 * 4 + (lane >> 4);
        const int gp = lane & 15;
        soff0 = (unsigned)(r0 * 256 + ((gp ^ (r0 & 15)) * 16));
        soff1 = (unsigned)(r1 * 256 + ((gp ^ (r1 & 15)) * 16));
    }

    const unsigned char* Bglob = Pn + (size_t)(oct * 1024) * DDIM;

#define STG(T, BUF)                                                          \
    do {                                                                     \
        async16(Bglob + (size_t)(T) * 16384 + soff0,                         \
                lds + (BUF) * 16384 + wv * 2048);                            \
        async16(Bglob + (size_t)(T) * 16384 + soff1,                         \
                lds + (BUF) * 16384 + wv * 2048 + 1024);                     \
    } while (0)

    float rowpart[16];
    #pragma unroll
    for (int g = 0; g < 16; ++g) rowpart[g] = 0.0f;

    // ---- Prologue: stage tiles 0..2, full drain (also covers A-loads) ----
    STG(0, 0); STG(1, 1); STG(2, 2);
    asm volatile("s_waitcnt vmcnt(0)" ::: "memory");
    __builtin_amdgcn_s_barrier();

    // ---- Main loop: 16 col-slots of 64 fp8 cols ----
    for (int i = 0; i < 16; ++i) {
        if (i > 0) {
            // tile i done; tiles i+1, i+2 (2 loads each) stay in flight
            if (i <= 13)      asm volatile("s_waitcnt vmcnt(4)" ::: "memory");
            else if (i == 14) asm volatile("s_waitcnt vmcnt(2)" ::: "memory");
            else              asm volatile("s_waitcnt vmcnt(0)" ::: "memory");
            __builtin_amdgcn_s_barrier();   // frees buf (i+3)&3
        }
        if (i + 3 < 16) STG(i + 3, (i + 3) & 3);

        const unsigned char* Bp = lds + (i & 3) * 16384;
        f32x16 acc0, acc1;
        #pragma unroll
        for (int g = 0; g < 16; ++g) { acc0[g] = 0.0f; acc1[g] = 0.0f; }

        #pragma unroll
        for (int kc = 0; kc < 4; ++kc) {
            A8 b0, b1;
            b0.h[0] = *(const int4v*)(Bp + bA + kterm[kc]);
            b0.h[1] = *(const int4v*)(Bp + bB + kterm[kc]);
            b1.h[0] = *(const int4v*)(Bp + bA + kterm[kc] + 8192);
            b1.h[1] = *(const int4v*)(Bp + bB + kterm[kc] + 8192);
            __builtin_amdgcn_s_setprio(1);
            acc0 = __builtin_amdgcn_mfma_scale_f32_32x32x64_f8f6f4(
                afr[kc].v, b0.v, acc0, 0, 0,
                0, 0x7F7F7F7F, 0, 0x7F7F7F7F);   // fp8/fp8, unit scales
            acc1 = __builtin_amdgcn_mfma_scale_f32_32x32x64_f8f6f4(
                afr[kc].v, b1.v, acc1, 0, 0,
                0, 0x7F7F7F7F, 0, 0x7F7F7F7F);
            __builtin_amdgcn_s_setprio(0);
        }

        // exp(5*sim) = 2^(sim*5*log2 e)
        #pragma unroll
        for (int g = 0; g < 16; ++g)
            rowpart[g] += fexp2(acc0[g] * 7.2134752044448169f)
                        + fexp2(acc1[g] * 7.2134752044448169f);
    }
#undef STG

    // ---- Epilogue: reduce 32 column-lanes, one atomic per row-slot ----
    // C/D: col = lane&31, row = (g&3) + 8*(g>>2) + 4*hi.
    #pragma unroll
    for (int g = 0; g < 16; ++g) {
        float s = rowpart[g];
        s += __shfl_xor(s, 1);
        s += __shfl_xor(s, 2);
        s += __shfl_xor(s, 4);
        s += __shfl_xor(s, 8);
        s += __shfl_xor(s, 16);
        if (m32 == 0) {
            const int grow = stripe * 256 + wv * 32
                           + (g & 3) + 8 * (g >> 2) + 4 * hi;
            atomicAdd(&rowsum[grow], s);
        }
    }

    // ---- Fused finalize: last block computes the loss ----
    __threadfence();
    __syncthreads();   // this block's atomics are visible
    if (tid == 0)
        ticket_s = __hip_atomic_fetch_add(counter, 1, __ATOMIC_ACQ_REL,
                                          __HIP_MEMORY_SCOPE_AGENT);
    __syncthreads();
    if (ticket_s == 255) {
        float part = 0.0f;
        for (int i = tid; i < NROWS; i += 512) {
            const float rs = __hip_atomic_load(&rowsum[i], __ATOMIC_RELAXED,
                                               __HIP_MEMORY_SCOPE_AGENT);
            part += __logf(rs) - 5.0f * possim[i];
        }
        #pragma unroll
        for (int d = 1; d < 64; d <<= 1) part += __shfl_xor(part, d);
        if ((tid & 63) == 0) ws8[wv] = part;
        __syncthreads();
        if (tid == 0) {
            float tot = 0.0f;
            #pragma unroll
            for (int w = 0; w < 8; ++w) tot += ws8[w];
            out[0] = tot * (1.0f / (float)NROWS);
        }
    }
}

extern "C" void kernel_launch(void* const* d_in, const int* in_sizes, int n_in,
                              void* d_out, int out_size, void* d_ws, size_t ws_size,
                              hipStream_t stream) {
    const float* U = (const float*)d_in[0];
    const float* P = (const float*)d_in[1];
    float* out = (float*)d_out;
    char* ws = (char*)d_ws;
    // ws: Un fp8 (2 MB) | Pn fp8 (2 MB) | ... | rowsum f32 @8 MB | possim | counter
    unsigned char* Un = (unsigned char*)ws;
    unsigned char* Pn = (unsigned char*)(ws + 2097152);
    float* rowsum = (float*)(ws + 8388608);
    float* possim = (float*)(ws + 8388608 + 32768);
    int* counter  = (int*)(ws + 8388608 + 65536);

    normalize_kernel<<<NROWS / 4, 256, 0, stream>>>(U, P, Un, Pn, possim, rowsum,
                                                    out, counter);
    sim_exp_rowsum<<<256, 512, 0, stream>>>(Un, Pn, rowsum, possim, counter, out);
}